// Round 2
// baseline (346.466 us; speedup 1.0000x reference)
//
#include <hip/hip_runtime.h>

// RingLoss on MI355X.
// loss = (1/N) * sum_r 0.5*log(n_r)  -  (1/(N*tau)) * sum_i diag(s12)_i
// where S = G G^T, G = [h1n; h2n] (8192 x 512), and n_r = ring sum of exp(S[r,:]/tau)
// excluding the top-409 and bottom-409 values of each row.
//
// ws layout: G bf16 (8 MB) | accums (256 B) | S-chunk bf16 (adaptive, multiples of
// 128 rows x 8192 cols x 2 B). Gram+ring are looped over row-chunks so any
// ws_size >= ~10.25 MB works; with ws_size >= ~136 MB it is a single chunk.

typedef unsigned short u16;
typedef __bf16 bf16x8 __attribute__((ext_vector_type(8)));
typedef float f32x4 __attribute__((ext_vector_type(4)));
typedef u16 u16x8 __attribute__((ext_vector_type(8)));

#define NROW 8192
#define NHALF 4096
#define DIM 512
#define RING_T 409      // int(4096 * 0.1)
#define NB 1024         // histogram buckets over [-1.05, 1.05]

__device__ inline u16 f2bf(float f) {
  unsigned u = __builtin_bit_cast(unsigned, f);
  unsigned r = (u + 0x7fffu + ((u >> 16) & 1u)) >> 16;  // RTNE
  return (u16)r;
}
__device__ inline float bf2f(u16 h) {
  unsigned u = ((unsigned)h) << 16;
  return __builtin_bit_cast(float, u);
}

// block = 256 threads (4 waves). Returns full block sum to all threads.
__device__ inline float block_sum(float x, volatile float* s4, int t) {
  #pragma unroll
  for (int off = 32; off > 0; off >>= 1) x += __shfl_down(x, off);
  __syncthreads();
  if ((t & 63) == 0) s4[t >> 6] = x;
  __syncthreads();
  return s4[0] + s4[1] + s4[2] + s4[3];
}

// ---------------- normalize: G[r] = row / max(||row||, 1e-12), bf16 ----------------
__global__ __launch_bounds__(256) void normalize_k(const float* __restrict__ h1,
                                                   const float* __restrict__ h2,
                                                   u16* __restrict__ G) {
  const int r = blockIdx.x;
  const int t = threadIdx.x;
  const float* src = (r < NHALF) ? (h1 + (size_t)r * DIM) : (h2 + (size_t)(r - NHALF) * DIM);
  float2 x = *(const float2*)(src + (t << 1));
  __shared__ float s4[4];
  float tot = block_sum(x.x * x.x + x.y * x.y, s4, t);
  float scale = 1.0f / fmaxf(sqrtf(tot), 1e-12f);
  unsigned pk = (unsigned)f2bf(x.x * scale) | ((unsigned)f2bf(x.y * scale) << 16);
  *(unsigned*)(G + (size_t)r * DIM + (t << 1)) = pk;
}

// ---------------- exact fp32 diagonal of s12, summed ----------------
__global__ __launch_bounds__(256) void diag_k(const float* __restrict__ h1,
                                              const float* __restrict__ h2,
                                              float* __restrict__ accums) {
  const int i = blockIdx.x, t = threadIdx.x;
  float2 a = *(const float2*)(h1 + (size_t)i * DIM + (t << 1));
  float2 b = *(const float2*)(h2 + (size_t)i * DIM + (t << 1));
  __shared__ float s4[4];
  float S11 = block_sum(a.x * a.x + a.y * a.y, s4, t);
  float S22 = block_sum(b.x * b.x + b.y * b.y, s4, t);
  float S12 = block_sum(a.x * b.x + a.y * b.y, s4, t);
  if (t == 0) {
    float d = S12 / (fmaxf(sqrtf(S11), 1e-12f) * fmaxf(sqrtf(S22), 1e-12f));
    atomicAdd(&accums[1], d);
  }
}

// ---------------- S = G G^T, bf16 MFMA 16x16x32, 128x128 tile, BK=32 ----------------
#define BK 32
#define LDK 40  // padded LDS stride (elements): 80 B rows -> ~2-way banks (free)

__global__ __launch_bounds__(256) void gram_gemm(const u16* __restrict__ G,
                                                 u16* __restrict__ S,
                                                 int row0) {
  __shared__ u16 As[128 * LDK];
  __shared__ u16 Bs[128 * LDK];
  const int t = threadIdx.x;
  const int lane = t & 63;
  const int wave = t >> 6;
  const int wm = wave >> 1, wn = wave & 1;   // 2x2 waves of 64x64
  const int brow = row0 + (blockIdx.y << 7), bcol = blockIdx.x << 7;
  const int fr = lane & 15, fg = lane >> 4;  // fragment row/col, k-group

  f32x4 acc[4][4] = {};

  for (int ks = 0; ks < DIM; ks += BK) {
    // reg-stage both tiles: 128 rows x 32 elems (64 B) each; 2 rounds x 256 thr x 16 B
    u16x8 ua[2], ub[2];
    #pragma unroll
    for (int q = 0; q < 2; ++q) {
      int cid = (q << 8) + t;
      int r = cid >> 2;
      int c = ((cid & 3) + r) & 3;  // chunk rotation (LDS write-bank spread)
      const int go = ks + c * 8;
      ua[q] = *(const u16x8*)(G + (size_t)(brow + r) * DIM + go);
      ub[q] = *(const u16x8*)(G + (size_t)(bcol + r) * DIM + go);
    }
    __syncthreads();  // prior iteration's frag reads complete
    #pragma unroll
    for (int q = 0; q < 2; ++q) {
      int cid = (q << 8) + t;
      int r = cid >> 2;
      int c = ((cid & 3) + r) & 3;
      *(u16x8*)(&As[r * LDK + c * 8]) = ua[q];
      *(u16x8*)(&Bs[r * LDK + c * 8]) = ub[q];
    }
    __syncthreads();

    // fragments: A[row = lane&15][k = (lane>>4)*8 + j], B[k][col = lane&15]
    bf16x8 af[4], bfr[4];
    #pragma unroll
    for (int m = 0; m < 4; ++m)
      af[m] = __builtin_bit_cast(bf16x8,
          *(const u16x8*)(&As[((wm << 6) + (m << 4) + fr) * LDK + (fg << 3)]));
    #pragma unroll
    for (int n = 0; n < 4; ++n)
      bfr[n] = __builtin_bit_cast(bf16x8,
          *(const u16x8*)(&Bs[((wn << 6) + (n << 4) + fr) * LDK + (fg << 3)]));
    #pragma unroll
    for (int m = 0; m < 4; ++m)
      #pragma unroll
      for (int n = 0; n < 4; ++n)
        acc[m][n] = __builtin_amdgcn_mfma_f32_16x16x32_bf16(af[m], bfr[n], acc[m][n], 0, 0, 0);
  }

  // epilogue: D row = (lane>>4)*4 + j, col = lane&15  (m89-verified layout)
  // S is the chunk buffer: local row index = global row - row0
  #pragma unroll
  for (int m = 0; m < 4; ++m)
    #pragma unroll
    for (int n = 0; n < 4; ++n) {
      int lrow = (blockIdx.y << 7) + (wm << 6) + (m << 4) + (fg << 2);
      int col = bcol + (wn << 6) + (n << 4) + fr;
      #pragma unroll
      for (int j = 0; j < 4; ++j)
        S[(size_t)(lrow + j) * NROW + col] = f2bf(acc[m][n][j]);
    }
}

// ---------------- per-row ring sum via histogram selection ----------------
__global__ __launch_bounds__(256) void ring_k(const u16* __restrict__ S,
                                              const float* __restrict__ taup,
                                              float* __restrict__ accums) {
  __shared__ unsigned cnt[NB];
  __shared__ unsigned sfx[NB];
  __shared__ float s4[4];
  __shared__ int bhi_s, blo_s;
  const int r = blockIdx.x, t = threadIdx.x;  // r = local chunk row
  const float inv_tau = 1.0f / taup[0];

  #pragma unroll
  for (int k = 0; k < 4; ++k) cnt[t + (k << 8)] = 0;
  __syncthreads();

  // load 32 values/thread, coalesced 16B chunks
  float v[32];
  const u16* row = S + (size_t)r * NROW;
  #pragma unroll
  for (int q = 0; q < 4; ++q) {
    u16x8 u = *(const u16x8*)(row + (((q << 8) + t) << 3));
    #pragma unroll
    for (int j = 0; j < 8; ++j) v[(q << 3) + j] = bf2f(u[j]);
  }
  #pragma unroll
  for (int i = 0; i < 32; ++i) {
    int b = (int)((v[i] + 1.05f) * 487.61905f);
    b = b < 0 ? 0 : (b > (NB - 1) ? (NB - 1) : b);
    atomicAdd(&cnt[b], 1u);
  }
  __syncthreads();

  // suffix scan: sfx[i] = count of elements in buckets >= i
  #pragma unroll
  for (int k = 0; k < 4; ++k) sfx[t + (k << 8)] = cnt[t + (k << 8)];
  __syncthreads();
  for (int off = 1; off < NB; off <<= 1) {
    unsigned tmp[4];
    #pragma unroll
    for (int k = 0; k < 4; ++k) {
      int i = t + (k << 8);
      tmp[k] = sfx[i] + ((i + off < NB) ? sfx[i + off] : 0u);
    }
    __syncthreads();
    #pragma unroll
    for (int k = 0; k < 4; ++k) sfx[t + (k << 8)] = tmp[k];
    __syncthreads();
  }

  // boundary buckets: bh holds the 409th-largest, bl the 409th-smallest
  #pragma unroll
  for (int k = 0; k < 4; ++k) {
    int i = t + (k << 8);
    unsigned ai = sfx[i];
    unsigned ae = (i + 1 < NB) ? sfx[i + 1] : 0u;
    if (ai >= RING_T && ae < RING_T) bhi_s = i;
    unsigned beq = NROW - ae;  // count <= bucket i
    unsigned blt = NROW - ai;  // count <  bucket i
    if (beq >= RING_T && blt < RING_T) blo_s = i;
  }
  __syncthreads();
  const int bh = bhi_s, bl = blo_s;

  float eTot = 0, eAb = 0, eHi = 0, eBe = 0, eLo = 0;
  #pragma unroll
  for (int i = 0; i < 32; ++i) {
    float e = __expf(v[i] * inv_tau);
    int b = (int)((v[i] + 1.05f) * 487.61905f);
    b = b < 0 ? 0 : (b > (NB - 1) ? (NB - 1) : b);
    eTot += e;
    if (b > bh) eAb += e;
    else if (b == bh) eHi += e;
    if (b < bl) eBe += e;
    else if (b == bl) eLo += e;
  }
  eTot = block_sum(eTot, s4, t);
  eAb  = block_sum(eAb, s4, t);
  eHi  = block_sum(eHi, s4, t);
  eBe  = block_sum(eBe, s4, t);
  eLo  = block_sum(eLo, s4, t);

  if (t == 0) {
    unsigned cAb = (bh + 1 < NB) ? sfx[bh + 1] : 0u;  // strictly above bucket bh
    unsigned cBe = NROW - sfx[bl];                    // strictly below bucket bl
    unsigned ch = cnt[bh], cl = cnt[bl];
    float sumTop = eAb + (ch ? (float)(RING_T - cAb) * (eHi / (float)ch) : 0.0f);
    float sumBot = eBe + (cl ? (float)(RING_T - cBe) * (eLo / (float)cl) : 0.0f);
    float n = eTot - sumTop - sumBot;
    atomicAdd(&accums[0], 0.5f * logf(n));
  }
}

__global__ void init_k(float* accums) {
  if (threadIdx.x < 2) accums[threadIdx.x] = 0.0f;
}

__global__ void final_k(const float* __restrict__ accums,
                        const float* __restrict__ taup,
                        float* __restrict__ out) {
  out[0] = (accums[0] - accums[1] / taup[0]) * (1.0f / (float)NHALF);
}

extern "C" void kernel_launch(void* const* d_in, const int* in_sizes, int n_in,
                              void* d_out, int out_size, void* d_ws, size_t ws_size,
                              hipStream_t stream) {
  const float* h1 = (const float*)d_in[0];
  const float* h2 = (const float*)d_in[1];
  // d_in[2] (labels y) is dead in the reference loss
  const float* taup = (const float*)d_in[3];
  float* out = (float*)d_out;

  char* ws = (char*)d_ws;
  u16* G = (u16*)ws;                                       // 8 MB
  float* accums = (float*)(ws + (size_t)8 * 1024 * 1024);  // 256 B reserved
  u16* Schunk = (u16*)(ws + (size_t)8 * 1024 * 1024 + 256);

  // adaptive S-chunking: rows per chunk, multiple of 128
  size_t avail = (ws_size > (size_t)8 * 1024 * 1024 + 256)
                     ? ws_size - (size_t)8 * 1024 * 1024 - 256 : 0;
  long long rpc = (long long)(avail / ((size_t)NROW * 2));
  rpc = (rpc / 128) * 128;
  if (rpc < 128) rpc = 128;        // last-resort assumption
  if (rpc > NROW) rpc = NROW;

  hipLaunchKernelGGL(init_k, dim3(1), dim3(64), 0, stream, accums);
  hipLaunchKernelGGL(normalize_k, dim3(NROW), dim3(256), 0, stream, h1, h2, G);
  hipLaunchKernelGGL(diag_k, dim3(NHALF), dim3(256), 0, stream, h1, h2, accums);

  for (int r0 = 0; r0 < NROW; r0 += (int)rpc) {
    int rows = (int)((r0 + rpc <= NROW) ? rpc : (NROW - r0));
    hipLaunchKernelGGL(gram_gemm, dim3(64, rows >> 7), dim3(256), 0, stream,
                       G, Schunk, r0);
    hipLaunchKernelGGL(ring_k, dim3(rows), dim3(256), 0, stream,
                       Schunk, taup, accums);
  }

  hipLaunchKernelGGL(final_k, dim3(1), dim3(1), 0, stream, accums, taup, out);
}

// Round 3
// 333.226 us; speedup vs baseline: 1.0397x; 1.0397x over previous
//
#include <hip/hip_runtime.h>

// RingLoss on MI355X.
// loss = (1/N) * sum_r 0.5*log(n_r)  -  (1/(N*tau)) * sum_i diag(s12)_i
// where S = G G^T, G = [h1n; h2n] (8192 x 512), and n_r = ring sum of exp(S[r,:]/tau)
// excluding the top-409 and bottom-409 values of each row (histogram-select).

typedef unsigned short u16;
typedef __bf16 bf16x8 __attribute__((ext_vector_type(8)));
typedef float f32x4 __attribute__((ext_vector_type(4)));
typedef u16 u16x8 __attribute__((ext_vector_type(8)));

#define NROW 8192
#define NHALF 4096
#define DIM 512
#define RING_T 409      // int(4096 * 0.1)
#define NB 256          // histogram buckets over [-1.05, 1.05]
#define BSCALE 121.904762f  // NB / 2.1

__device__ inline u16 f2bf(float f) {
  unsigned u = __builtin_bit_cast(unsigned, f);
  unsigned r = (u + 0x7fffu + ((u >> 16) & 1u)) >> 16;  // RTNE
  return (u16)r;
}
__device__ inline float bf2f(u16 h) {
  unsigned u = ((unsigned)h) << 16;
  return __builtin_bit_cast(float, u);
}
__device__ inline int bucket_of(float v) {
  int b = (int)((v + 1.05f) * BSCALE);
  return b < 0 ? 0 : (b > (NB - 1) ? (NB - 1) : b);
}

// block = 256 threads (4 waves). Returns full block sum to all threads.
__device__ inline float block_sum(float x, volatile float* s4, int t) {
  #pragma unroll
  for (int off = 32; off > 0; off >>= 1) x += __shfl_down(x, off);
  __syncthreads();
  if ((t & 63) == 0) s4[t >> 6] = x;
  __syncthreads();
  return s4[0] + s4[1] + s4[2] + s4[3];
}

// ---------------- normalize: G[r] = row / max(||row||, 1e-12), bf16 ----------------
__global__ __launch_bounds__(256) void normalize_k(const float* __restrict__ h1,
                                                   const float* __restrict__ h2,
                                                   u16* __restrict__ G) {
  const int r = blockIdx.x;
  const int t = threadIdx.x;
  const float* src = (r < NHALF) ? (h1 + (size_t)r * DIM) : (h2 + (size_t)(r - NHALF) * DIM);
  float2 x = *(const float2*)(src + (t << 1));
  __shared__ float s4[4];
  float tot = block_sum(x.x * x.x + x.y * x.y, s4, t);
  float scale = 1.0f / fmaxf(sqrtf(tot), 1e-12f);
  unsigned pk = (unsigned)f2bf(x.x * scale) | ((unsigned)f2bf(x.y * scale) << 16);
  *(unsigned*)(G + (size_t)r * DIM + (t << 1)) = pk;
}

// ---------------- exact fp32 diagonal of s12, summed ----------------
__global__ __launch_bounds__(256) void diag_k(const float* __restrict__ h1,
                                              const float* __restrict__ h2,
                                              float* __restrict__ accums) {
  const int i = blockIdx.x, t = threadIdx.x;
  float2 a = *(const float2*)(h1 + (size_t)i * DIM + (t << 1));
  float2 b = *(const float2*)(h2 + (size_t)i * DIM + (t << 1));
  __shared__ float s4[4];
  float S11 = block_sum(a.x * a.x + a.y * a.y, s4, t);
  float S22 = block_sum(b.x * b.x + b.y * b.y, s4, t);
  float S12 = block_sum(a.x * b.x + a.y * b.y, s4, t);
  if (t == 0) {
    float d = S12 / (fmaxf(sqrtf(S11), 1e-12f) * fmaxf(sqrtf(S22), 1e-12f));
    atomicAdd(&accums[1], d);
  }
}

// ---------------- S = G G^T: 128x128 tile, BK=32, global_load_lds staging ----------------
#define BK 32

__device__ inline void gload_lds16(const u16* g, u16* lds_base) {
  __builtin_amdgcn_global_load_lds(
      (const __attribute__((address_space(1))) void*)g,
      (__attribute__((address_space(3))) void*)lds_base, 16, 0, 0);
}

__global__ __launch_bounds__(256) void gram_gemm(const u16* __restrict__ G,
                                                 u16* __restrict__ S,
                                                 int row0) {
  __shared__ u16 As[128 * BK];   // linear [128][32] (global_load_lds needs linear dest)
  __shared__ u16 Bs[128 * BK];
  const int t = threadIdx.x;
  const int lane = t & 63;
  const int wave = t >> 6;
  const int wm = wave >> 1, wn = wave & 1;   // 2x2 waves of 64x64
  const int brow = row0 + (blockIdx.y << 7), bcol = blockIdx.x << 7;
  const int fr = lane & 15, fg = lane >> 4;  // fragment row/col, k-group

  // staging geometry: chunk = 16 rows x 32 cols = 1 KB = 64 lanes x 16 B
  // lane l covers row (l>>2), col-quarter (l&3)*8 within the chunk
  const int srow = lane >> 2;
  const int scol = (lane & 3) << 3;
  const int chA0 = wave, chA1 = wave + 4;    // wave-uniform chunk ids

  f32x4 acc[4][4] = {};

  for (int ks = 0; ks < DIM; ks += BK) {
    __syncthreads();  // prior iteration's fragment reads complete
    gload_lds16(G + (size_t)(brow + (chA0 << 4) + srow) * DIM + ks + scol, As + (chA0 << 9));
    gload_lds16(G + (size_t)(brow + (chA1 << 4) + srow) * DIM + ks + scol, As + (chA1 << 9));
    gload_lds16(G + (size_t)(bcol + (chA0 << 4) + srow) * DIM + ks + scol, Bs + (chA0 << 9));
    gload_lds16(G + (size_t)(bcol + (chA1 << 4) + srow) * DIM + ks + scol, Bs + (chA1 << 9));
    __syncthreads();  // compiler drains vmcnt(0) before barrier -> staging visible

    bf16x8 af[4], bfr[4];
    #pragma unroll
    for (int m = 0; m < 4; ++m)
      af[m] = __builtin_bit_cast(bf16x8,
          *(const u16x8*)(&As[(((wm << 6) + (m << 4) + fr) << 5) + (fg << 3)]));
    #pragma unroll
    for (int n = 0; n < 4; ++n)
      bfr[n] = __builtin_bit_cast(bf16x8,
          *(const u16x8*)(&Bs[(((wn << 6) + (n << 4) + fr) << 5) + (fg << 3)]));
    #pragma unroll
    for (int m = 0; m < 4; ++m)
      #pragma unroll
      for (int n = 0; n < 4; ++n)
        acc[m][n] = __builtin_amdgcn_mfma_f32_16x16x32_bf16(af[m], bfr[n], acc[m][n], 0, 0, 0);
  }

  // epilogue: D row = (lane>>4)*4 + j, col = lane&15  (verified round 2)
  #pragma unroll
  for (int m = 0; m < 4; ++m)
    #pragma unroll
    for (int n = 0; n < 4; ++n) {
      int lrow = (blockIdx.y << 7) + (wm << 6) + (m << 4) + (fg << 2);
      int col = bcol + (wn << 6) + (n << 4) + fr;
      #pragma unroll
      for (int j = 0; j < 4; ++j)
        S[(size_t)(lrow + j) * NROW + col] = f2bf(acc[m][n][j]);
    }
}

// ---------------- per-row ring sum via histogram selection (v2) ----------------
__global__ __launch_bounds__(256) void ring_k(const u16* __restrict__ S,
                                              const float* __restrict__ taup,
                                              float* __restrict__ accums) {
  __shared__ unsigned hist4[4 * NB];   // per-wave histogram copies
  __shared__ unsigned cnt[NB];
  __shared__ unsigned sfx[NB];         // sfx[b] = # elements in buckets >= b
  __shared__ unsigned wavetot[4];
  __shared__ float red[4 * 8];
  __shared__ int bhl[2];
  const int r = blockIdx.x, t = threadIdx.x;
  const int lane = t & 63, w = t >> 6;
  const float inv_tau = 1.0f / taup[0];

  #pragma unroll
  for (int k = 0; k < 4; ++k) hist4[t + (k << 8)] = 0;
  __syncthreads();

  // load 32 values/thread, coalesced 16B chunks
  float v[32];
  const u16* row = S + (size_t)r * NROW;
  #pragma unroll
  for (int q = 0; q < 4; ++q) {
    u16x8 u = *(const u16x8*)(row + (((q << 8) + t) << 3));
    #pragma unroll
    for (int j = 0; j < 8; ++j) v[(q << 3) + j] = bf2f(u[j]);
  }
  unsigned* myhist = &hist4[w << 8];
  #pragma unroll
  for (int i = 0; i < 32; ++i) atomicAdd(&myhist[bucket_of(v[i])], 1u);
  __syncthreads();

  // merge copies; suffix scan via shfl (bucket b = thread t)
  unsigned c = hist4[t] + hist4[t + 256] + hist4[t + 512] + hist4[t + 768];
  cnt[t] = c;
  unsigned x = c;
  #pragma unroll
  for (int off = 1; off < 64; off <<= 1) {
    unsigned y = __shfl_down(x, off);
    if (lane + off < 64) x += y;
  }
  // lane l of wave w now holds sum over buckets [w*64+l .. w*64+63]
  unsigned wt = __shfl(x, 0);
  if (lane == 0) wavetot[w] = wt;
  __syncthreads();
  unsigned hi = 0;
  #pragma unroll
  for (int k = 0; k < 4; ++k) hi += (k > w) ? wavetot[k] : 0u;
  sfx[t] = x + hi;
  __syncthreads();

  // boundary buckets
  {
    unsigned ai = sfx[t];
    unsigned ae = (t < NB - 1) ? sfx[t + 1] : 0u;
    if (ai >= RING_T && ae < RING_T) bhl[0] = t;          // holds 409th-largest
    unsigned beq = NROW - ae;  // count <= bucket t
    unsigned blt = NROW - ai;  // count <  bucket t
    if (beq >= RING_T && blt < RING_T) bhl[1] = t;        // holds 409th-smallest
  }
  __syncthreads();
  const int bh = bhl[0], bl = bhl[1];

  float eTot = 0, eAb = 0, eHi = 0, eBe = 0, eLo = 0;
  #pragma unroll
  for (int i = 0; i < 32; ++i) {
    float e = __expf(v[i] * inv_tau);
    int b = bucket_of(v[i]);
    eTot += e;
    eAb += (b > bh) ? e : 0.0f;
    eHi += (b == bh) ? e : 0.0f;
    eBe += (b < bl) ? e : 0.0f;
    eLo += (b == bl) ? e : 0.0f;
  }
  // fused 5-way reduce: wave-shuffle, then one barrier
  float acc5[5] = {eTot, eAb, eHi, eBe, eLo};
  #pragma unroll
  for (int q = 0; q < 5; ++q)
    #pragma unroll
    for (int off = 32; off > 0; off >>= 1) acc5[q] += __shfl_down(acc5[q], off);
  if (lane == 0)
    #pragma unroll
    for (int q = 0; q < 5; ++q) red[(w << 3) + q] = acc5[q];
  __syncthreads();

  if (t == 0) {
    float s5[5];
    #pragma unroll
    for (int q = 0; q < 5; ++q)
      s5[q] = red[q] + red[8 + q] + red[16 + q] + red[24 + q];
    unsigned cAb = (bh + 1 < NB) ? sfx[bh + 1] : 0u;  // strictly above bucket bh
    unsigned cBe = NROW - sfx[bl];                    // strictly below bucket bl
    unsigned ch = cnt[bh], cl = cnt[bl];
    float sumTop = s5[1] + (ch ? (float)(RING_T - cAb) * (s5[2] / (float)ch) : 0.0f);
    float sumBot = s5[3] + (cl ? (float)(RING_T - cBe) * (s5[4] / (float)cl) : 0.0f);
    float n = s5[0] - sumTop - sumBot;
    atomicAdd(&accums[0], 0.5f * logf(n));
  }
}

__global__ void init_k(float* accums) {
  if (threadIdx.x < 2) accums[threadIdx.x] = 0.0f;
}

__global__ void final_k(const float* __restrict__ accums,
                        const float* __restrict__ taup,
                        float* __restrict__ out) {
  out[0] = (accums[0] - accums[1] / taup[0]) * (1.0f / (float)NHALF);
}

extern "C" void kernel_launch(void* const* d_in, const int* in_sizes, int n_in,
                              void* d_out, int out_size, void* d_ws, size_t ws_size,
                              hipStream_t stream) {
  const float* h1 = (const float*)d_in[0];
  const float* h2 = (const float*)d_in[1];
  // d_in[2] (labels y) is dead in the reference loss
  const float* taup = (const float*)d_in[3];
  float* out = (float*)d_out;

  char* ws = (char*)d_ws;
  u16* G = (u16*)ws;                                       // 8 MB
  float* accums = (float*)(ws + (size_t)8 * 1024 * 1024);  // 256 B reserved
  u16* Schunk = (u16*)(ws + (size_t)8 * 1024 * 1024 + 256);

  // adaptive S-chunking: rows per chunk, multiple of 128
  size_t avail = (ws_size > (size_t)8 * 1024 * 1024 + 256)
                     ? ws_size - (size_t)8 * 1024 * 1024 - 256 : 0;
  long long rpc = (long long)(avail / ((size_t)NROW * 2));
  rpc = (rpc / 128) * 128;
  if (rpc < 128) rpc = 128;        // last-resort assumption
  if (rpc > NROW) rpc = NROW;

  hipLaunchKernelGGL(init_k, dim3(1), dim3(64), 0, stream, accums);
  hipLaunchKernelGGL(normalize_k, dim3(NROW), dim3(256), 0, stream, h1, h2, G);
  hipLaunchKernelGGL(diag_k, dim3(NHALF), dim3(256), 0, stream, h1, h2, accums);

  for (int r0 = 0; r0 < NROW; r0 += (int)rpc) {
    int rows = (int)((r0 + rpc <= NROW) ? rpc : (NROW - r0));
    hipLaunchKernelGGL(gram_gemm, dim3(64, rows >> 7), dim3(256), 0, stream,
                       G, Schunk, r0);
    hipLaunchKernelGGL(ring_k, dim3(rows), dim3(256), 0, stream,
                       Schunk, taup, accums);
  }

  hipLaunchKernelGGL(final_k, dim3(1), dim3(1), 0, stream, accums, taup, out);
}